// Round 8
// baseline (121.648 us; speedup 1.0000x reference)
//
#include <hip/hip_runtime.h>
#include <hip/hip_bf16.h>
#include <stdint.h>

// KAN layer: out[b,o] = sum_{i,k} basis(tanh(x[b,i]))[k] * coeffs[o,i,k]
// GEMM M=8192, N=512, K=4096.  cvt coeffs->Bt bf16 (ws) ; basis(x)->A (ws) ;
// gemm(A,Bt)->out.
// R7 post-mortem: LDS-BW reduction was neutral -> LDS BW not binding. R6/R7
// are 1 block/CU: every __syncthreads+vmcnt(0) drain stalls the WHOLE CU
// (no independent block to compute through it; m114/m97: need >=2-3 blocks).
// R8: BM=128, BN=64, 256 thr (4 waves 2x2, wave tile 64x32), dbuf one-barrier
// K-loop, LDS 48KB -> grid 512 = 2 INDEPENDENT blocks/CU with decoupled
// barriers. XCD decode: 8mt x 8nt per XCD (Bt 4MB L2-resident, A streams).

#define M_TOTAL 8192
#define N_DIM   512
#define K_DIM   4096
#define BM 128
#define BN 64
#define BK 64
#define NTILES (K_DIM / BK)              // 64
#define ABYTES (BM * BK * 2)             // 16 KB
#define BUF_BYTES ((BM + BN) * BK * 2)   // 24 KB per LDS buffer

typedef __attribute__((ext_vector_type(8))) short short8;   // 8 x bf16
typedef __attribute__((ext_vector_type(4))) float f32x4;

typedef const __attribute__((address_space(1))) uint32_t ga_u32;
typedef __attribute__((address_space(3))) uint32_t ls_u32;

__device__ __forceinline__ void gload_lds16(const void* g, void* l) {
  // async global->LDS, 16B/lane; LDS dest = wave-uniform base + lane*16
  __builtin_amdgcn_global_load_lds((ga_u32*)(uintptr_t)g,
                                   (ls_u32*)(uint32_t)(uintptr_t)l, 16, 0, 0);
}

__device__ __forceinline__ uint32_t f2bf(float f) {
  uint32_t u = __builtin_bit_cast(uint32_t, f);
  return (u + 0x7FFFu + ((u >> 16) & 1u)) >> 16;
}

// cardinal cubic B-spline on uniform knots h=2/11; t=tanh(x) in (-1,1).
// 8 basis slots as 4xu32 packed bf16: w0..w3 land at slots c-3..c, rest 0.
__device__ __forceinline__ void basis_slots(float xv, uint32_t o[4]) {
  xv = fminf(15.f, fmaxf(-15.f, xv));
  float e  = __expf(2.0f * xv);
  float t  = (e - 1.0f) * __builtin_amdgcn_rcpf(e + 1.0f);
  float uf = (t + 1.0f) * 5.5f;            // /h
  int   c  = (int)uf;  c = c > 10 ? 10 : c;
  float u  = uf - (float)c;
  float u2 = u * u, u3 = u2 * u, om = 1.0f - u;
  float w0 = om * om * om * (1.0f / 6.0f);
  float w1 = (3.0f * u3 - 6.0f * u2 + 4.0f) * (1.0f / 6.0f);
  float w2 = (-3.0f * u3 + 3.0f * u2 + 3.0f * u + 1.0f) * (1.0f / 6.0f);
  float w3 = u3 * (1.0f / 6.0f);
  uint32_t p01 = f2bf(w0) | (f2bf(w1) << 16);
  uint32_t p23 = f2bf(w2) | (f2bf(w3) << 16);
  uint64_t W = (uint64_t)p01 | ((uint64_t)p23 << 32);
  int d = c - 3;                            // slot of w0, in [-3, 7]
  uint64_t lo = (d < 0) ? (W >> ((-d) * 16))
              : ((d < 4) ? (W << (d * 16)) : 0ull);
  uint64_t hi = (d <= 0) ? 0ull
              : ((d < 4) ? (W >> ((4 - d) * 16)) : (W << ((d - 4) * 16)));
  o[0] = (uint32_t)lo; o[1] = (uint32_t)(lo >> 32);
  o[2] = (uint32_t)hi; o[3] = (uint32_t)(hi >> 32);
}

// ---------------- basis kernel: one (b,i) per thread, 16B store --------------
__global__ __launch_bounds__(256) void basis_kernel(const float* __restrict__ x,
                                                    __hip_bfloat16* __restrict__ A,
                                                    int total) {
  int idx = blockIdx.x * 256 + threadIdx.x;
  if (idx >= total) return;
  uint32_t o[4];
  basis_slots(x[idx], o);
  reinterpret_cast<int4*>(A)[idx] = make_int4(o[0], o[1], o[2], o[3]);
}

// ---------------- coeff cast: [512][512][8] fp32 -> bf16 (== B^T[512][4096]) --
__global__ __launch_bounds__(256) void cvt_kernel(const float* __restrict__ c,
                                                  __hip_bfloat16* __restrict__ Bt,
                                                  int total8) {
  int idx = blockIdx.x * 256 + threadIdx.x;
  if (idx >= total8) return;
  const float4* cp = reinterpret_cast<const float4*>(c) + (size_t)idx * 2;
  float4 a = cp[0], b = cp[1];
  union { unsigned short us[8]; int4 v; } pk;
  pk.us[0] = (unsigned short)f2bf(a.x); pk.us[1] = (unsigned short)f2bf(a.y);
  pk.us[2] = (unsigned short)f2bf(a.z); pk.us[3] = (unsigned short)f2bf(a.w);
  pk.us[4] = (unsigned short)f2bf(b.x); pk.us[5] = (unsigned short)f2bf(b.y);
  pk.us[6] = (unsigned short)f2bf(b.z); pk.us[7] = (unsigned short)f2bf(b.w);
  reinterpret_cast<int4*>(Bt)[idx] = pk.v;
}

// ---------------- GEMM: C[m,n] = sum_k A[m,k]*Bt[n,k] ------------------------
// 256 thr = 4 waves (2x2), wave tile 64x32 (4x2 frags), dbuf one-barrier loop.
__global__ __launch_bounds__(256) void gemm_kernel(
    const __hip_bfloat16* __restrict__ A,   // [8192][4096]
    const __hip_bfloat16* __restrict__ Bt,  // [512][4096]
    float* __restrict__ C) {                // [8192][512]
  __shared__ __hip_bfloat16 lds[2 * (BM + BN) * BK];   // 48 KB

  const int tid   = threadIdx.x;
  const int wid   = tid >> 6;
  const int lane  = tid & 63;
  const int quad  = lane >> 4;
  const int l16   = lane & 15;
  const int waveM = wid >> 1;               // 0..1
  const int waveN = wid & 1;                // 0..1

  // XCD decode: per XCD 64 blocks = 8 mt x 8 nt; Bt (4MB) L2-resident,
  // A stripes (1MB each, shared by the 8 nt blocks) stream through L2.
  const int b  = blockIdx.x;
  const int q  = b >> 3;                    // 0..63
  const int mt = (b & 7) * 8 + (q >> 3);    // 0..63
  const int nt = q & 7;                     // 0..7
  const int m0 = mt * BM;
  const int n0 = nt * BN;

  // staging: slot s -> (row, phys chunk p); source chunk cc = p ^ (row&7)
  // A: 1024 slots (4 insts/thread) at buf+0; B: 512 slots (2) at buf+16KB
  uint32_t aGlob[4], sAOff[4], bGlob[2], sBOff[2];
#pragma unroll
  for (int t = 0; t < 4; ++t) {
    int s = t * 256 + tid, row = s >> 3, p = s & 7, cc = p ^ (row & 7);
    sAOff[t] = (uint32_t)s * 16u;
    aGlob[t] = (uint32_t)(m0 + row) * K_DIM + (uint32_t)cc * 8u;
  }
#pragma unroll
  for (int t = 0; t < 2; ++t) {
    int s = t * 256 + tid, row = s >> 3, p = s & 7, cc = p ^ (row & 7);
    sBOff[t] = (uint32_t)ABYTES + (uint32_t)s * 16u;
    bGlob[t] = (uint32_t)(n0 + row) * K_DIM + (uint32_t)cc * 8u;
  }

  // fragment read offsets within a buffer (A at +0, B at +16KB)
  uint32_t aOff[2][4], bOff[2][2];
#pragma unroll
  for (int kk = 0; kk < 2; ++kk) {
    int c = kk * 4 + quad;
#pragma unroll
    for (int mi = 0; mi < 4; ++mi) {
      int row = waveM * 64 + mi * 16 + l16;
      aOff[kk][mi] = (uint32_t)(row * 8 + (c ^ (row & 7))) * 16u;
    }
#pragma unroll
    for (int ni = 0; ni < 2; ++ni) {
      int row = waveN * 32 + ni * 16 + l16;
      bOff[kk][ni] = (uint32_t)ABYTES + (uint32_t)(row * 8 + (c ^ (row & 7))) * 16u;
    }
  }

  char* ldsc = (char*)lds;

  f32x4 acc[4][2];
#pragma unroll
  for (int mi = 0; mi < 4; ++mi)
#pragma unroll
    for (int ni = 0; ni < 2; ++ni)
      acc[mi][ni] = (f32x4){0.f, 0.f, 0.f, 0.f};

  // prologue: stage tile 0 into buffer 0
#pragma unroll
  for (int t = 0; t < 4; ++t) gload_lds16(A + aGlob[t], ldsc + sAOff[t]);
#pragma unroll
  for (int t = 0; t < 2; ++t) gload_lds16(Bt + bGlob[t], ldsc + sBOff[t]);

  for (int it = 0; it < NTILES; ++it) {
    const int cur = it & 1;
    char* bufc = ldsc + cur * BUF_BYTES;
    __syncthreads();                        // staging for tile it drained
    if (it + 1 < NTILES) {                  // stage it+1 under compute of it
      char* bufn = ldsc + (1 - cur) * BUF_BYTES;
      uint32_t kt = (uint32_t)(it + 1) * BK;
#pragma unroll
      for (int t = 0; t < 4; ++t)
        gload_lds16(A + aGlob[t] + kt, bufn + sAOff[t]);
#pragma unroll
      for (int t = 0; t < 2; ++t)
        gload_lds16(Bt + bGlob[t] + kt, bufn + sBOff[t]);
    }
#pragma unroll
    for (int kk = 0; kk < 2; ++kk) {
      short8 af[4], bf[2];
#pragma unroll
      for (int mi = 0; mi < 4; ++mi)
        af[mi] = *reinterpret_cast<const short8*>(bufc + aOff[kk][mi]);
#pragma unroll
      for (int ni = 0; ni < 2; ++ni)
        bf[ni] = *reinterpret_cast<const short8*>(bufc + bOff[kk][ni]);
#pragma unroll
      for (int mi = 0; mi < 4; ++mi)
#pragma unroll
        for (int ni = 0; ni < 2; ++ni)
          acc[mi][ni] = __builtin_amdgcn_mfma_f32_16x16x32_bf16(
              af[mi], bf[ni], acc[mi][ni], 0, 0, 0);
    }
  }

  // epilogue: D row = quad*4 + r, col = l16 (m89/m91-verified C/D layout)
#pragma unroll
  for (int mi = 0; mi < 4; ++mi) {
#pragma unroll
    for (int ni = 0; ni < 2; ++ni) {
      int col = n0 + waveN * 32 + ni * 16 + l16;
#pragma unroll
      for (int r = 0; r < 4; ++r) {
        int row = m0 + waveM * 64 + mi * 16 + quad * 4 + r;
        C[(size_t)row * N_DIM + col] = acc[mi][ni][r];
      }
    }
  }
}

extern "C" void kernel_launch(void* const* d_in, const int* in_sizes, int n_in,
                              void* d_out, int out_size, void* d_ws, size_t ws_size,
                              hipStream_t stream) {
  const float* x    = (const float*)d_in[0];   // [8192,512]
  const float* coef = (const float*)d_in[1];   // [512,512,8]
  float* out = (float*)d_out;                  // [8192,512]

  __hip_bfloat16* Bt = (__hip_bfloat16*)d_ws;                       // 4 MB
  __hip_bfloat16* A  = (__hip_bfloat16*)((char*)d_ws + (size_t)4 * 1024 * 1024);
  // A = 64 MB; ws is ~268 MB (observed via harness poison fill), fits.

  const int total8 = N_DIM * K_DIM / 8;        // 262144
  cvt_kernel<<<(total8 + 255) / 256, 256, 0, stream>>>(coef, Bt, total8);

  const int total = M_TOTAL * 512;             // (b,i) pairs
  basis_kernel<<<total / 256, 256, 0, stream>>>(x, A, total);

  gemm_kernel<<<(M_TOTAL / BM) * (N_DIM / BN), 256, 0, stream>>>(A, Bt, out);
}